// Round 9
// baseline (134.534 us; speedup 1.0000x reference)
//
#include <hip/hip_runtime.h>

// LocallyConnected1d via bf16 MFMA: out[b,o,l] = sum_{i,k} x[b,i,l+k-4]*w[i,o,k,l] + bias[o,l]
// 512 per-l GEMMs (M=b=64, N=o (8 real + 8 zero-pad), K=576 k-major).
//
// R9 = R8 skeleton (LT=16/OT=8, w read once, XCD-local os slices, Bs dbuf +
// 3-slot ring, 1 barrier/step) + two fixes:
//  1. Xs XOR swizzle: R8's staging writes were 6-way bank conflicts (lw-stride
//     64*XBS = 0 mod 32 words -> qq invisible in banks; 6.0M conflict cycles =
//     ~20%/CU). Store ii^(8*(qq&3)), read with akg^rot, rot=8*((lw>>2)&3).
//     Writes now 2-way (free), reads stay aligned b128.
//  2. Producer/consumer: waves 0..7 stage only; waves 8..15 MFMA only, 2
//     b-tiles each (Bf register-reused across bt: B-reads 64->32/step).

#define CIN   64
#define COUT  64
#define SEQ   512
#define KS    9
#define LT    16
#define OT    8
#define LWIN  24
#define WSTR  (COUT*KS*SEQ)            // weight i-stride (floats)
#define XBS   40                       // Xs b-stride (ush): 32 i + 8 pad
#define XLW   (64*XBS)                 // Xs lw-stride = 2560 ush
#define XS_ELEMS (LWIN*XLW)            // 61440 ush = 120 KB
#define BOS   40                       // Bs o-stride (ush)
#define BLS   (OT*BOS + 8)             // Bs l-stride = 328 ush
#define BSLOT (LT*BLS)                 // 5248 ush per buffer
#define ZOFF  (XS_ELEMS + 2*BSLOT)     // zero region for n>=8 B-frag reads
#define LDS_USH (ZOFF + 64)            // 72000 ush
#define LDS_BYTES (LDS_USH*2)          // 144000 B -> 1 block/CU
#define NSTEP 18                       // 2 i-halves x 9 k-taps

typedef __attribute__((ext_vector_type(8))) short bf16x8;
typedef __attribute__((ext_vector_type(4))) float f32x4;

__device__ __forceinline__ uint pack2bf(float a0, float a1) {
    uint u0 = __float_as_uint(a0) + 0x8000u;
    uint u1 = __float_as_uint(a1) + 0x8000u;
    return __builtin_amdgcn_perm(u1, u0, 0x07060302);  // (bf(a1)<<16)|bf(a0)
}

__global__ __launch_bounds__(1024, 4)
void lc1d_mfma(const float* __restrict__ x, const float* __restrict__ w,
               const float* __restrict__ bias, float* __restrict__ out)
{
    extern __shared__ ushort lds[];
    ushort* Xs = lds;                    // [lw 0..23][b 0..63][ii' 0..31 swizzled]
    ushort* BsB = lds + XS_ELEMS;        // 2 x [l 0..15][o 0..7][kk 0..31]

    const int tid  = threadIdx.x;
    const int lane = tid & 63;
    const int wvid = tid >> 6;           // 0..15
    const int lt = blockIdx.x >> 3;      // 0..31
    const int os = blockIdx.x & 7;       // 0..7 == XCD id
    const int l0 = lt * LT;
    const int o0 = os * OT;

    // ---- stager mapping (waves 0..7): 64-B-contiguous l spans ----
    const bool stager = (wvid < 8);
    const int lf  = tid & 3;             // float4 within the 16-l span
    const int oo  = (tid >> 2) & 7;      // o
    const int ipp = (tid >> 5) & 15;     // i-pair within 32-i half

    const float* wbase = w + ((size_t)(2*ipp)*COUT + (o0 + oo))*(KS*SEQ) + l0 + lf*4;

    float4 rA[3], rB[3];                 // 3-slot ring, i-pair per slot

    // step s: ih = s/9 (i-half), k = s%9 (tap)
    #define LOAD_RING(sl, s) if (stager && (s) < NSTEP) {                        \
        const int ih_ = (s) / 9, k_ = (s) - 9*ih_;                               \
        const float* p_ = wbase + (size_t)ih_*32*WSTR + k_*SEQ;                  \
        rA[sl] = *(const float4*)p_;                                             \
        rB[sl] = *(const float4*)(p_ + WSTR);                                    \
    }

    // transpose+cvt ring slot -> Bs parity (s&1): b32 of i-pair at [l][o][kk]
    #define WRITE_BS(sl, s) if (stager) {                                        \
        ushort* dst_ = BsB + ((s)&1)*BSLOT + oo*BOS + 2*ipp;                     \
        _Pragma("unroll")                                                        \
        for (int dl = 0; dl < 4; ++dl) {                                         \
            uint pk_ = pack2bf((&rA[sl].x)[dl], (&rB[sl].x)[dl]);                \
            *(uint*)(dst_ + (lf*4+dl)*BLS) = pk_;                                \
        }                                                                        \
    }

    // stage Xs for i-half ih, XOR-swizzled: Xs[lw][b][ii ^ 8*(qq&3)]
    #define STAGE_XS(ih) {                                                       \
        const int qq  = tid & 7;                                                 \
        const int rp0 = tid >> 3;                                                \
        if (qq < 6) {                                                            \
            const int sw = 8*(qq & 3);                                           \
            _Pragma("unroll")                                                    \
            for (int it = 0; it < 8; ++it) {                                     \
                const int rp = rp0 + it*128;                                     \
                const int b_ = rp >> 4, ip_ = rp & 15;                           \
                const float* s0 = x + ((size_t)(b_*CIN) + (ih)*32 + 2*ip_)*SEQ   \
                                    + (l0 - 4) + qq*4;                           \
                float4 v0 = make_float4(0.f,0.f,0.f,0.f), v1 = v0;               \
                if (!((lt == 0 && qq == 0) || (lt == 31 && qq == 5))) {          \
                    v0 = *(const float4*)s0;                                     \
                    v1 = *(const float4*)(s0 + SEQ);                             \
                }                                                                \
                ushort* d_ = Xs + b_*XBS + ((2*ip_) ^ sw);                       \
                _Pragma("unroll")                                                \
                for (int dl = 0; dl < 4; ++dl)                                   \
                    *(uint*)(d_ + (qq*4+dl)*XLW) = pack2bf((&v0.x)[dl],          \
                                                           (&v1.x)[dl]);         \
            }                                                                    \
        }                                                                        \
    }

    // ---- consumer constants (waves 8..15): 1 l-group, 2 b-tiles each ----
    const int cw  = wvid - 8;                          // 0..7 (consumers)
    const int lg  = cw & 3;                            // l-group
    const int bth = cw >> 2;                           // b-tile pair 0/1
    const int am  = (lane & 15) * XBS;
    const int akg = (lane >> 4) * 8;                   // kgrp*8 (pre-XOR)
    const int boff = (lane & 15)*BOS + (lane >> 4)*8;
    const bool nhi = (lane & 15) >= 8;                 // dead o lanes -> zeros
    const ushort* zptr = lds + ZOFF + (lane >> 4)*8;   // shared (broadcast) zeros

    f32x4 acc[2][4];
    #pragma unroll
    for (int a = 0; a < 2; ++a)
        #pragma unroll
        for (int j = 0; j < 4; ++j) acc[a][j] = (f32x4)0.0f;

    #define DO_MFMA(s) if (!stager) {                                            \
        const int k_ = (s) % 9;                                                  \
        const ushort* BsS = BsB + ((s)&1)*BSLOT;                                 \
        _Pragma("unroll")                                                        \
        for (int dl = 0; dl < 4; ++dl) {                                         \
            const int ll = lg*4 + dl;                                            \
            const int lw = ll + k_;                                              \
            const int rot = ((lw >> 2) & 3) * 8;                                 \
            const ushort* Bp = nhi ? zptr : (BsS + ll*BLS + boff);               \
            bf16x8 Bf = *(const bf16x8*)Bp;                                      \
            const ushort* Ar = Xs + lw*XLW + am + (akg ^ rot);                   \
            _Pragma("unroll")                                                    \
            for (int b2 = 0; b2 < 2; ++b2) {                                     \
                bf16x8 Af = *(const bf16x8*)(Ar + (bth*2 + b2)*(16*XBS));        \
                acc[b2][dl] = __builtin_amdgcn_mfma_f32_16x16x32_bf16(           \
                                  Af, Bf, acc[b2][dl], 0, 0, 0);                 \
            }                                                                    \
        }                                                                        \
    }

    // one barrier per step: stagers fill Bs parity (s+1)&1 while consumers
    // read parity s&1.
    #define STEP(s) {                                                            \
        if ((s) < NSTEP-1) WRITE_BS(((s)+1)%3, (s)+1)                            \
        LOAD_RING(((s)+1)%3, (s)+4)                                              \
        DO_MFMA(s)                                                               \
        __syncthreads();                                                         \
    }

    // ---- prologue ----
    LOAD_RING(0, 0)
    LOAD_RING(1, 1)
    LOAD_RING(2, 2)
    if (tid < 64) lds[ZOFF + tid] = 0;
    STAGE_XS(0)
    WRITE_BS(0, 0)
    LOAD_RING(0, 3)
    __syncthreads();   // Xs(ih0) + Bs(step0) + zero region ready

    STEP(0)  STEP(1)  STEP(2)  STEP(3)  STEP(4)
    STEP(5)  STEP(6)  STEP(7)  STEP(8)

    STAGE_XS(1)        // step<=8 Xs reads done at STEP(8)'s barrier
    __syncthreads();

    STEP(9)  STEP(10) STEP(11) STEP(12) STEP(13)
    STEP(14) STEP(15) STEP(16) STEP(17)

    // ---- epilogue (consumers, o-lanes < 8 only) ----
    if (!stager && !nhi) {
        const int og = o0 + (lane & 15);
        const int rb = (lane >> 4)*4;
        #pragma unroll
        for (int dl = 0; dl < 4; ++dl) {
            const int lgl = l0 + lg*4 + dl;
            const float bv = bias[og*SEQ + lgl];
            #pragma unroll
            for (int b2 = 0; b2 < 2; ++b2) {
                #pragma unroll
                for (int r = 0; r < 4; ++r) {
                    const int bg = (bth*2 + b2)*16 + rb + r;
                    out[((size_t)(bg*COUT + og))*SEQ + lgl] = acc[b2][dl][r] + bv;
                }
            }
        }
    }
}

extern "C" void kernel_launch(void* const* d_in, const int* in_sizes, int n_in,
                              void* d_out, int out_size, void* d_ws, size_t ws_size,
                              hipStream_t stream) {
    const float* x    = (const float*)d_in[0];
    const float* wgt  = (const float*)d_in[1];
    const float* bias = (const float*)d_in[2];
    float* out        = (float*)d_out;

    hipFuncSetAttribute((const void*)lc1d_mfma,
                        hipFuncAttributeMaxDynamicSharedMemorySize, LDS_BYTES);
    dim3 grid(256);   // blockIdx = lt*8 + os: os == XCD id; lt line-mates co-XCD
    lc1d_mfma<<<grid, 1024, LDS_BYTES, stream>>>(x, wgt, bias, out);
}